// Round 20
// baseline (4214.286 us; speedup 1.0000x reference)
//
#include <hip/hip_runtime.h>
#include <cstdint>
#include <cstddef>

#define Bb 8
#define Nn 8192
#define Cc 64
#define NPOINT 2048
#define NSAMPLE 32
#define CIN 67      // C + 3
#define D1 64
#define D2 128
#define QGAP 624
#define ULP_WIN 4u
#define FPST 1024
#define NPTS 8      // Nn / FPST

// Wave-wide max of a u64 key via DPP (verified passing R15/R16/R18/R19):
// row_shr 1/2/4/8 + row_bcast15 + row_bcast31; max in lane 63; readlane.
__device__ __forceinline__ unsigned long long wave_max_u64(unsigned long long k) {
    unsigned int hi = (unsigned int)(k >> 32), lo = (unsigned int)k;
#define DPP_STEP(CTRL) { \
    unsigned int h2 = (unsigned int)__builtin_amdgcn_update_dpp(0, (int)hi, CTRL, 0xf, 0xf, true); \
    unsigned int l2 = (unsigned int)__builtin_amdgcn_update_dpp(0, (int)lo, CTRL, 0xf, 0xf, true); \
    if ((h2 > hi) || (h2 == hi && l2 > lo)) { hi = h2; lo = l2; } }
    DPP_STEP(0x111)
    DPP_STEP(0x112)
    DPP_STEP(0x114)
    DPP_STEP(0x118)
    DPP_STEP(0x142)
    DPP_STEP(0x143)
#undef DPP_STEP
    unsigned int mh = (unsigned int)__builtin_amdgcn_readlane((int)hi, 63);
    unsigned int ml = (unsigned int)__builtin_amdgcn_readlane((int)lo, 63);
    return ((unsigned long long)mh << 32) | ml;
}

// ---------------------------------------------------------------------------
// FPS == R19 (passing, 3659us) with ONE structural change: the full dist
// mirror (8 LDS writes/thread/iter, ~700 LDS-pipe cycles) becomes a SPARSE
// mirror — write sdist[idx] only when dist[idx] actually decreases
// (~30 writes/iter block-wide after warmup). Single persistent buffer
// (init 1e10) + a second barrier for race-freedom: writes for iter it+1
// cannot start until all waves pass B2(it), and probe reads are pre-B2.
// Value path bit-identical (same fmin chain, same keys, same probe).
// ---------------------------------------------------------------------------
__global__ __launch_bounds__(FPST) void fps_kernel(
    const float* __restrict__ xyz,      // (B,N,3)
    float* __restrict__ out_xyz,        // (B,NPOINT,3)
    float* __restrict__ out_idx_f)      // (B,NPOINT) float view of output 2
{
    const int b = blockIdx.x;
    const float* xb = xyz + (size_t)b * Nn * 3;
    const int tid = threadIdx.x;

    float px[NPTS], py[NPTS], pz[NPTS], dist[NPTS];
#pragma unroll
    for (int j = 0; j < NPTS; ++j) {
        int p = tid * NPTS + j;
        px[j] = xb[p * 3 + 0];
        py[j] = xb[p * 3 + 1];
        pz[j] = xb[p * 3 + 2];
        dist[j] = 1e10f;
    }

    __shared__ float sdist[Nn];                 // 32 KB persistent mirror
    __shared__ unsigned long long skey[2][16];  // wave maxima (parity)

    // init mirror to the initial dist value
#pragma unroll
    for (int j = 0; j < NPTS; ++j) sdist[tid * NPTS + j] = 1e10f;

    float lx = xb[0], ly = xb[1], lz = xb[2];
    int win = 0;

    // register-buffered results: thread t owns iterations t and t+1024
    float r0i = 0.0f, r0x = lx, r0y = ly, r0z = lz;   // valid for t=0 (it=0)
    float r1i = 0.0f, r1x = 0.0f, r1y = 0.0f, r1z = 0.0f;

    __syncthreads();   // publish mirror init

    for (int it = 1; it < NPOINT; ++it) {
        const int s = it & 1;

        float best = -1.0f;
        int bj = 0;
#pragma unroll
        for (int j = 0; j < NPTS; ++j) {
            float dx = __fsub_rn(px[j], lx);
            float dy = __fsub_rn(py[j], ly);
            float dz = __fsub_rn(pz[j], lz);
            // numpy sequential order: (dx*dx + dy*dy) + dz*dz
            float d2 = __fadd_rn(__fadd_rn(__fmul_rn(dx, dx), __fmul_rn(dy, dy)),
                                 __fmul_rn(dz, dz));
            // sparse mirror update: only when dist actually decreases
            if (d2 < dist[j]) {
                dist[j] = d2;
                sdist[tid * NPTS + j] = d2;
            }
            // ascending j == ascending global idx: strict > keeps first occ
            if (dist[j] > best) { best = dist[j]; bj = j; }
        }
        const int bi = tid * NPTS + bj;

        // key: larger dist wins; equal dist -> larger ~idx == smaller idx wins
        unsigned long long key =
            ((unsigned long long)__float_as_uint(best) << 32) |
            (unsigned int)(~bi);
        unsigned long long wmax = wave_max_u64(key);
        if ((tid & 63) == 0) skey[s][tid >> 6] = wmax;
        __syncthreads();                         // B1: mirror + keys published

        // second stage: per-lane read of the 16 wave keys (duplicated 4x per
        // wave) + proven wave_max -> block max, uniform on every thread
        unsigned long long kk = wave_max_u64(skey[s][tid & 15]);
        const unsigned int Mb = (unsigned int)(kk >> 32);
        const int w = (int)(~(unsigned int)kk);

        bool plus_ok = false, minus_ok = false;
        if (w + QGAP < Nn) {
            unsigned int vb = __float_as_uint(sdist[w + QGAP]);
            plus_ok = (Mb - vb) <= ULP_WIN;
        }
        if (w - QGAP >= 0) {
            unsigned int vb = __float_as_uint(sdist[w - QGAP]);
            minus_ok = (Mb - vb) <= ULP_WIN;
        }
        win = plus_ok ? (w + QGAP) : (minus_ok ? (w - QGAP) : w);

        // winner coords: broadcast global loads (L2-resident)
        lx = xb[win * 3 + 0];
        ly = xb[win * 3 + 1];
        lz = xb[win * 3 + 2];

        // capture result into the owning thread's registers (no memory ops)
        if (tid == (it & (FPST - 1))) {
            if (it < FPST) { r0i = (float)win; r0x = lx; r0y = ly; r0z = lz; }
            else           { r1i = (float)win; r1x = lx; r1y = ly; r1z = lz; }
        }
        __syncthreads();                         // B2: probe reads done before
                                                 //     next iter's writes
    }

    // bulk write-out: thread t -> entries t and t+1024
    {
        const size_t base = (size_t)b * NPOINT;
        out_idx_f[base + tid] = r0i;
        out_idx_f[base + tid + FPST] = r1i;
        out_xyz[(base + tid) * 3 + 0] = r0x;
        out_xyz[(base + tid) * 3 + 1] = r0y;
        out_xyz[(base + tid) * 3 + 2] = r0z;
        out_xyz[(base + tid + FPST) * 3 + 0] = r1x;
        out_xyz[(base + tid + FPST) * 3 + 1] = r1y;
        out_xyz[(base + tid + FPST) * 3 + 2] = r1z;
    }
}

// ---------------------------------------------------------------------------
// Ball query, f32; r2 = 0.04f. One wave per centroid, ordered scan, first
// NSAMPLE hits, pad with first hit (8191 if none). (Passed every round.)
// ---------------------------------------------------------------------------
__global__ __launch_bounds__(256) void ballq_kernel(
    const float* __restrict__ xyz,       // (B,N,3)
    const float* __restrict__ new_xyz,   // (B,NPOINT,3)
    int* __restrict__ gidx)              // (B,NPOINT,NSAMPLE)
{
    const int lane = threadIdx.x & 63;
    const int cent = blockIdx.x * 4 + (threadIdx.x >> 6);
    const int b = cent >> 11;            // / NPOINT
    const float* xb = xyz + (size_t)b * Nn * 3;
    const float cx = new_xyz[cent * 3 + 0];
    const float cy = new_xyz[cent * 3 + 1];
    const float cz = new_xyz[cent * 3 + 2];
    int* g = gidx + (size_t)cent * NSAMPLE;

    const float r2 = 0.04f;
    int cnt = 0;
    int first = -1;
    for (int base = 0; base < Nn && cnt < NSAMPLE; base += 64) {
        int pt = base + lane;
        float dx = __fsub_rn(xb[pt * 3 + 0], cx);
        float dy = __fsub_rn(xb[pt * 3 + 1], cy);
        float dz = __fsub_rn(xb[pt * 3 + 2], cz);
        float d2 = __fadd_rn(__fadd_rn(__fmul_rn(dx, dx), __fmul_rn(dy, dy)),
                             __fmul_rn(dz, dz));
        bool in = !(d2 > r2);
        unsigned long long m = __ballot(in);
        if (first < 0 && m) first = base + __ffsll((unsigned long long)m) - 1;
        int before = __popcll(m & ((1ull << lane) - 1ull));
        int pos = cnt + before;
        if (in && pos < NSAMPLE) g[pos] = pt;
        cnt += __popcll(m);
    }
    int total = cnt < NSAMPLE ? cnt : NSAMPLE;
    int pv = first >= 0 ? first : (Nn - 1);
    if (lane < NSAMPLE && lane >= total) g[lane] = pv;
}

// ---------------------------------------------------------------------------
// Grouping + MLP(67->64->128, relu) + max-pool. One block per centroid.
// Vectorized LDS traffic (b128 reads, broadcast rows); per-accumulator fma
// sequence (ascending c) is UNCHANGED -> bit-identical to prior rounds.
// ---------------------------------------------------------------------------
__global__ __launch_bounds__(256) void group_mlp_kernel(
    const float* __restrict__ xyz, const float* __restrict__ features,
    const float* __restrict__ W1, const float* __restrict__ b1,
    const float* __restrict__ W2, const float* __restrict__ b2,
    const float* __restrict__ new_xyz, const int* __restrict__ gidx,
    float* __restrict__ out_feat)        // (B, D2, NPOINT)
{
    const int cent = blockIdx.x;
    const int b = cent >> 11;
    const int p = cent & (NPOINT - 1);
    const int tid = threadIdx.x;

    __shared__ __align__(16) float sW1t[D1][CIN + 1];     // transposed W1, 17.4 KB
    __shared__ __align__(16) float sg[NSAMPLE][CIN + 1];  // 8.7 KB
    __shared__ __align__(16) float sh1[NSAMPLE][D1];      // 8 KB
    __shared__ float smax[2][D2];
    __shared__ int   sidx[NSAMPLE];
    __shared__ float sc[3];

    // W1 (c-major) -> transposed LDS [d][c]; coalesced global reads
    for (int i = tid; i < CIN * D1; i += 256) {
        int c = i >> 6, d = i & 63;
        sW1t[d][c] = W1[i];
    }
    if (tid < NSAMPLE) sidx[tid] = gidx[(size_t)cent * NSAMPLE + tid];
    if (tid < 3) sc[tid] = new_xyz[cent * 3 + tid];
    __syncthreads();

    // gather: wave = sample-group, lane = channel
    {
        const int c = tid & 63;
        const int sgp = tid >> 6;
#pragma unroll
        for (int k = 0; k < 8; ++k) {
            int s = sgp * 8 + k;
            int pi = sidx[s];
            sg[s][3 + c] = features[((size_t)b * Nn + pi) * Cc + c];
            if (c < 3)
                sg[s][c] = xyz[((size_t)b * Nn + pi) * 3 + c] - sc[c];
        }
    }
    __syncthreads();

    // layer 1: thread = (sample-group, out-channel d); 8 samples per thread
    // b128 weight read + 8 broadcast b128 sg reads per 4-channel chunk
    {
        const int d = tid & 63;
        const int sgp = tid >> 6;
        float acc[8];
        const float bb = b1[d];
#pragma unroll
        for (int k = 0; k < 8; ++k) acc[k] = bb;
        for (int c4 = 0; c4 < 64; c4 += 4) {
            float4 wv = *(const float4*)&sW1t[d][c4];
#pragma unroll
            for (int k = 0; k < 8; ++k) {
                float4 gv = *(const float4*)&sg[sgp * 8 + k][c4];
                acc[k] = fmaf(gv.x, wv.x, acc[k]);
                acc[k] = fmaf(gv.y, wv.y, acc[k]);
                acc[k] = fmaf(gv.z, wv.z, acc[k]);
                acc[k] = fmaf(gv.w, wv.w, acc[k]);
            }
        }
#pragma unroll
        for (int c = 64; c < CIN; ++c) {
            float w = sW1t[d][c];
#pragma unroll
            for (int k = 0; k < 8; ++k)
                acc[k] = fmaf(sg[sgp * 8 + k][c], w, acc[k]);
        }
#pragma unroll
        for (int k = 0; k < 8; ++k)
            sh1[sgp * 8 + k][d] = fmaxf(acc[k], 0.0f);
    }
    __syncthreads();

    // layer 2 + partial max-pool: thread = (half, out-channel d2); 16 samples
    // broadcast b128 sh1 reads + 4 batched coalesced W2 global scalars/chunk
    {
        const int d2 = tid & 127;
        const int half = tid >> 7;
        float acc[16];
        const float bb = b2[d2];
#pragma unroll
        for (int k = 0; k < 16; ++k) acc[k] = bb;
        for (int c4 = 0; c4 < D1; c4 += 4) {
            float w0 = W2[(c4 + 0) * D2 + d2];
            float w1 = W2[(c4 + 1) * D2 + d2];
            float w2 = W2[(c4 + 2) * D2 + d2];
            float w3 = W2[(c4 + 3) * D2 + d2];
#pragma unroll
            for (int k = 0; k < 16; ++k) {
                float4 hv = *(const float4*)&sh1[half * 16 + k][c4];
                acc[k] = fmaf(hv.x, w0, acc[k]);
                acc[k] = fmaf(hv.y, w1, acc[k]);
                acc[k] = fmaf(hv.z, w2, acc[k]);
                acc[k] = fmaf(hv.w, w3, acc[k]);
            }
        }
        float m = 0.0f;   // relu(h) >= 0, so max over relu == max(acc..., 0)
#pragma unroll
        for (int k = 0; k < 16; ++k) m = fmaxf(m, acc[k]);
        smax[half][d2] = m;
    }
    __syncthreads();
    if (tid < D2) {
        float m = fmaxf(smax[0][tid], smax[1][tid]);
        out_feat[((size_t)b * D2 + tid) * NPOINT + p] = m;
    }
}

extern "C" void kernel_launch(void* const* d_in, const int* in_sizes, int n_in,
                              void* d_out, int out_size, void* d_ws, size_t ws_size,
                              hipStream_t stream) {
    const float* xyz      = (const float*)d_in[0];
    const float* features = (const float*)d_in[1];
    const float* W1       = (const float*)d_in[2];
    const float* b1       = (const float*)d_in[3];
    const float* W2       = (const float*)d_in[4];
    const float* b2       = (const float*)d_in[5];

    float* out      = (float*)d_out;
    float* out_xyz  = out;                                   // B*NPOINT*3
    float* out_feat = out + (size_t)Bb * NPOINT * 3;         // B*D2*NPOINT
    float* out_idxf = out_feat + (size_t)Bb * D2 * NPOINT;   // B*NPOINT

    int* gidx = (int*)d_ws;                                  // B*NPOINT*NSAMPLE ints

    fps_kernel<<<Bb, FPST, 0, stream>>>(xyz, out_xyz, out_idxf);
    ballq_kernel<<<(Bb * NPOINT) / 4, 256, 0, stream>>>(xyz, out_xyz, gidx);
    group_mlp_kernel<<<Bb * NPOINT, 256, 0, stream>>>(xyz, features, W1, b1, W2, b2,
                                                      out_xyz, gidx, out_feat);
}

// Round 21
// 2565.828 us; speedup vs baseline: 1.6425x; 1.6425x over previous
//
#include <hip/hip_runtime.h>
#include <cstdint>
#include <cstddef>

#define Bb 8
#define Nn 8192
#define Cc 64
#define NPOINT 2048
#define NSAMPLE 32
#define CIN 67      // C + 3
#define D1 64
#define D2 128
#define QGAP 624
#define ULP_WIN 4u
#define FPST 1024
#define NPTS 8      // Nn / FPST

// 64-lane u32 max via DPP (same control codes as the R15-R19 proven u64
// reduce, but 2 inst/step); result returned uniform via readlane 63.
// bound_ctrl=true fills 0, identity for dist-bit patterns (dist >= 0).
__device__ __forceinline__ unsigned int wave_umax_dpp(unsigned int v) {
#define USTEP(CTRL) { \
    unsigned int o = (unsigned int)__builtin_amdgcn_update_dpp(0, (int)v, CTRL, 0xf, 0xf, true); \
    v = (v > o) ? v : o; }
    USTEP(0x111)  // row_shr:1
    USTEP(0x112)  // row_shr:2
    USTEP(0x114)  // row_shr:4
    USTEP(0x118)  // row_shr:8
    USTEP(0x142)  // row_bcast:15
    USTEP(0x143)  // row_bcast:31
#undef USTEP
    return (unsigned int)__builtin_amdgcn_readlane((int)v, 63);
}

// ---------------------------------------------------------------------------
// FPS == R19 (passing, 3659us fps) with ONE lever: both reduce stages use
// u32 DPP umax + ballot/ffsll/readlane instead of u64 compare-select chains.
// Order-equivalence: dist >= 0 so f32 bit order == u32 order; tie-break
// first-occurrence preserved because ownership is contiguous (lower lane ==
// lower global index; lanes 0-15 hold waves 0-15 in index order).
// Value path (dist chain, probe, carry) bit-identical to R11.
// ---------------------------------------------------------------------------
__global__ __launch_bounds__(FPST) void fps_kernel(
    const float* __restrict__ xyz,      // (B,N,3)
    float* __restrict__ out_xyz,        // (B,NPOINT,3)
    float* __restrict__ out_idx_f)      // (B,NPOINT) float view of output 2
{
    const int b = blockIdx.x;
    const float* xb = xyz + (size_t)b * Nn * 3;
    const int tid = threadIdx.x;

    float px[NPTS], py[NPTS], pz[NPTS], dist[NPTS];
#pragma unroll
    for (int j = 0; j < NPTS; ++j) {
        int p = tid * NPTS + j;
        px[j] = xb[p * 3 + 0];
        py[j] = xb[p * 3 + 1];
        pz[j] = xb[p * 3 + 2];
        dist[j] = 1e10f;
    }

    __shared__ __align__(16) float sdist[2][Nn];   // 64 KB dist mirror (parity)
    __shared__ unsigned long long skey[2][16];     // wave (dist,~idx) keys

    float lx = xb[0], ly = xb[1], lz = xb[2];
    int win = 0;

    // register-buffered results: thread t owns iterations t and t+1024
    float r0i = 0.0f, r0x = lx, r0y = ly, r0z = lz;   // valid for t=0 (it=0)
    float r1i = 0.0f, r1x = 0.0f, r1y = 0.0f, r1z = 0.0f;

    for (int it = 1; it < NPOINT; ++it) {
        const int s = it & 1;

        float best = -1.0f;
        int bj = 0;
#pragma unroll
        for (int j = 0; j < NPTS; ++j) {
            float dx = __fsub_rn(px[j], lx);
            float dy = __fsub_rn(py[j], ly);
            float dz = __fsub_rn(pz[j], lz);
            // numpy sequential order: (dx*dx + dy*dy) + dz*dz
            float d2 = __fadd_rn(__fadd_rn(__fmul_rn(dx, dx), __fmul_rn(dy, dy)),
                                 __fmul_rn(dz, dz));
            float dj = fminf(dist[j], d2);
            dist[j] = dj;
            // ascending j == ascending global idx: strict > keeps first occ
            if (dj > best) { best = dj; bj = j; }
        }
        const int bi = tid * NPTS + bj;

        // vectorized mirror: 2 x ds_write_b128 (32B-aligned)
        *(float4*)&sdist[s][tid * NPTS]     = make_float4(dist[0], dist[1], dist[2], dist[3]);
        *(float4*)&sdist[s][tid * NPTS + 4] = make_float4(dist[4], dist[5], dist[6], dist[7]);

        // stage 1: intra-wave u32 max + lowest-lane tie-break (first occ)
        {
            const unsigned int bbits = __float_as_uint(best);
            const unsigned int wmaxb = wave_umax_dpp(bbits);
            unsigned long long msk = __ballot(bbits == wmaxb);
            int l = __ffsll(msk) - 1;
            int widx = __builtin_amdgcn_readlane(bi, l);
            if ((tid & 63) == 0)
                skey[s][tid >> 6] =
                    ((unsigned long long)wmaxb << 32) | (unsigned int)(~widx);
        }
        __syncthreads();                         // THE barrier

        // stage 2: cross-wave u32 max over the 16 keys (duplicated 4x/wave)
        const unsigned long long k2 = skey[s][tid & 15];
        const unsigned int v2 = (unsigned int)(k2 >> 32);
        const unsigned int i2 = (unsigned int)k2;       // = ~idx
        const unsigned int Mb = wave_umax_dpp(v2);
        unsigned long long msk2 = __ballot(v2 == Mb);
        const int l2 = __ffsll(msk2) - 1;               // in [0,15]: lowest wave
        const unsigned int ni = (unsigned int)__builtin_amdgcn_readlane((int)i2, l2);
        const int w = (int)(~ni);

        bool plus_ok = false, minus_ok = false;
        if (w + QGAP < Nn) {
            unsigned int vb = __float_as_uint(sdist[s][w + QGAP]);
            plus_ok = (Mb - vb) <= ULP_WIN;
        }
        if (w - QGAP >= 0) {
            unsigned int vb = __float_as_uint(sdist[s][w - QGAP]);
            minus_ok = (Mb - vb) <= ULP_WIN;
        }
        win = plus_ok ? (w + QGAP) : (minus_ok ? (w - QGAP) : w);

        // winner coords: broadcast global loads (L2-resident)
        lx = xb[win * 3 + 0];
        ly = xb[win * 3 + 1];
        lz = xb[win * 3 + 2];

        // capture result into the owning thread's registers (no memory ops)
        if (tid == (it & (FPST - 1))) {
            if (it < FPST) { r0i = (float)win; r0x = lx; r0y = ly; r0z = lz; }
            else           { r1i = (float)win; r1x = lx; r1y = ly; r1z = lz; }
        }
    }

    // bulk write-out: thread t -> entries t and t+1024
    {
        const size_t base = (size_t)b * NPOINT;
        out_idx_f[base + tid] = r0i;
        out_idx_f[base + tid + FPST] = r1i;
        out_xyz[(base + tid) * 3 + 0] = r0x;
        out_xyz[(base + tid) * 3 + 1] = r0y;
        out_xyz[(base + tid) * 3 + 2] = r0z;
        out_xyz[(base + tid + FPST) * 3 + 0] = r1x;
        out_xyz[(base + tid + FPST) * 3 + 1] = r1y;
        out_xyz[(base + tid + FPST) * 3 + 2] = r1z;
    }
}

// ---------------------------------------------------------------------------
// Ball query, f32; r2 = 0.04f. One wave per centroid, ordered scan, first
// NSAMPLE hits, pad with first hit (8191 if none). (Passed every round.)
// ---------------------------------------------------------------------------
__global__ __launch_bounds__(256) void ballq_kernel(
    const float* __restrict__ xyz,       // (B,N,3)
    const float* __restrict__ new_xyz,   // (B,NPOINT,3)
    int* __restrict__ gidx)              // (B,NPOINT,NSAMPLE)
{
    const int lane = threadIdx.x & 63;
    const int cent = blockIdx.x * 4 + (threadIdx.x >> 6);
    const int b = cent >> 11;            // / NPOINT
    const float* xb = xyz + (size_t)b * Nn * 3;
    const float cx = new_xyz[cent * 3 + 0];
    const float cy = new_xyz[cent * 3 + 1];
    const float cz = new_xyz[cent * 3 + 2];
    int* g = gidx + (size_t)cent * NSAMPLE;

    const float r2 = 0.04f;
    int cnt = 0;
    int first = -1;
    for (int base = 0; base < Nn && cnt < NSAMPLE; base += 64) {
        int pt = base + lane;
        float dx = __fsub_rn(xb[pt * 3 + 0], cx);
        float dy = __fsub_rn(xb[pt * 3 + 1], cy);
        float dz = __fsub_rn(xb[pt * 3 + 2], cz);
        float d2 = __fadd_rn(__fadd_rn(__fmul_rn(dx, dx), __fmul_rn(dy, dy)),
                             __fmul_rn(dz, dz));
        bool in = !(d2 > r2);
        unsigned long long m = __ballot(in);
        if (first < 0 && m) first = base + __ffsll((unsigned long long)m) - 1;
        int before = __popcll(m & ((1ull << lane) - 1ull));
        int pos = cnt + before;
        if (in && pos < NSAMPLE) g[pos] = pt;
        cnt += __popcll(m);
    }
    int total = cnt < NSAMPLE ? cnt : NSAMPLE;
    int pv = first >= 0 ? first : (Nn - 1);
    if (lane < NSAMPLE && lane >= total) g[lane] = pv;
}

// ---------------------------------------------------------------------------
// Grouping + MLP(67->64->128, relu) + max-pool. One block per centroid.
// Vectorized LDS traffic (b128 reads, broadcast rows); per-accumulator fma
// sequence (ascending c) is UNCHANGED -> bit-identical to prior rounds.
// ---------------------------------------------------------------------------
__global__ __launch_bounds__(256) void group_mlp_kernel(
    const float* __restrict__ xyz, const float* __restrict__ features,
    const float* __restrict__ W1, const float* __restrict__ b1,
    const float* __restrict__ W2, const float* __restrict__ b2,
    const float* __restrict__ new_xyz, const int* __restrict__ gidx,
    float* __restrict__ out_feat)        // (B, D2, NPOINT)
{
    const int cent = blockIdx.x;
    const int b = cent >> 11;
    const int p = cent & (NPOINT - 1);
    const int tid = threadIdx.x;

    __shared__ __align__(16) float sW1t[D1][CIN + 1];     // transposed W1, 17.4 KB
    __shared__ __align__(16) float sg[NSAMPLE][CIN + 1];  // 8.7 KB
    __shared__ __align__(16) float sh1[NSAMPLE][D1];      // 8 KB
    __shared__ float smax[2][D2];
    __shared__ int   sidx[NSAMPLE];
    __shared__ float sc[3];

    // W1 (c-major) -> transposed LDS [d][c]; coalesced global reads
    for (int i = tid; i < CIN * D1; i += 256) {
        int c = i >> 6, d = i & 63;
        sW1t[d][c] = W1[i];
    }
    if (tid < NSAMPLE) sidx[tid] = gidx[(size_t)cent * NSAMPLE + tid];
    if (tid < 3) sc[tid] = new_xyz[cent * 3 + tid];
    __syncthreads();

    // gather: wave = sample-group, lane = channel
    {
        const int c = tid & 63;
        const int sgp = tid >> 6;
#pragma unroll
        for (int k = 0; k < 8; ++k) {
            int s = sgp * 8 + k;
            int pi = sidx[s];
            sg[s][3 + c] = features[((size_t)b * Nn + pi) * Cc + c];
            if (c < 3)
                sg[s][c] = xyz[((size_t)b * Nn + pi) * 3 + c] - sc[c];
        }
    }
    __syncthreads();

    // layer 1: thread = (sample-group, out-channel d); 8 samples per thread
    // b128 weight read + 8 broadcast b128 sg reads per 4-channel chunk
    {
        const int d = tid & 63;
        const int sgp = tid >> 6;
        float acc[8];
        const float bb = b1[d];
#pragma unroll
        for (int k = 0; k < 8; ++k) acc[k] = bb;
        for (int c4 = 0; c4 < 64; c4 += 4) {
            float4 wv = *(const float4*)&sW1t[d][c4];
#pragma unroll
            for (int k = 0; k < 8; ++k) {
                float4 gv = *(const float4*)&sg[sgp * 8 + k][c4];
                acc[k] = fmaf(gv.x, wv.x, acc[k]);
                acc[k] = fmaf(gv.y, wv.y, acc[k]);
                acc[k] = fmaf(gv.z, wv.z, acc[k]);
                acc[k] = fmaf(gv.w, wv.w, acc[k]);
            }
        }
#pragma unroll
        for (int c = 64; c < CIN; ++c) {
            float w = sW1t[d][c];
#pragma unroll
            for (int k = 0; k < 8; ++k)
                acc[k] = fmaf(sg[sgp * 8 + k][c], w, acc[k]);
        }
#pragma unroll
        for (int k = 0; k < 8; ++k)
            sh1[sgp * 8 + k][d] = fmaxf(acc[k], 0.0f);
    }
    __syncthreads();

    // layer 2 + partial max-pool: thread = (half, out-channel d2); 16 samples
    // broadcast b128 sh1 reads + 4 batched coalesced W2 global scalars/chunk
    {
        const int d2 = tid & 127;
        const int half = tid >> 7;
        float acc[16];
        const float bb = b2[d2];
#pragma unroll
        for (int k = 0; k < 16; ++k) acc[k] = bb;
        for (int c4 = 0; c4 < D1; c4 += 4) {
            float w0 = W2[(c4 + 0) * D2 + d2];
            float w1 = W2[(c4 + 1) * D2 + d2];
            float w2 = W2[(c4 + 2) * D2 + d2];
            float w3 = W2[(c4 + 3) * D2 + d2];
#pragma unroll
            for (int k = 0; k < 16; ++k) {
                float4 hv = *(const float4*)&sh1[half * 16 + k][c4];
                acc[k] = fmaf(hv.x, w0, acc[k]);
                acc[k] = fmaf(hv.y, w1, acc[k]);
                acc[k] = fmaf(hv.z, w2, acc[k]);
                acc[k] = fmaf(hv.w, w3, acc[k]);
            }
        }
        float m = 0.0f;   // relu(h) >= 0, so max over relu == max(acc..., 0)
#pragma unroll
        for (int k = 0; k < 16; ++k) m = fmaxf(m, acc[k]);
        smax[half][d2] = m;
    }
    __syncthreads();
    if (tid < D2) {
        float m = fmaxf(smax[0][tid], smax[1][tid]);
        out_feat[((size_t)b * D2 + tid) * NPOINT + p] = m;
    }
}

extern "C" void kernel_launch(void* const* d_in, const int* in_sizes, int n_in,
                              void* d_out, int out_size, void* d_ws, size_t ws_size,
                              hipStream_t stream) {
    const float* xyz      = (const float*)d_in[0];
    const float* features = (const float*)d_in[1];
    const float* W1       = (const float*)d_in[2];
    const float* b1       = (const float*)d_in[3];
    const float* W2       = (const float*)d_in[4];
    const float* b2       = (const float*)d_in[5];

    float* out      = (float*)d_out;
    float* out_xyz  = out;                                   // B*NPOINT*3
    float* out_feat = out + (size_t)Bb * NPOINT * 3;         // B*D2*NPOINT
    float* out_idxf = out_feat + (size_t)Bb * D2 * NPOINT;   // B*NPOINT

    int* gidx = (int*)d_ws;                                  // B*NPOINT*NSAMPLE ints

    fps_kernel<<<Bb, FPST, 0, stream>>>(xyz, out_xyz, out_idxf);
    ballq_kernel<<<(Bb * NPOINT) / 4, 256, 0, stream>>>(xyz, out_xyz, gidx);
    group_mlp_kernel<<<Bb * NPOINT, 256, 0, stream>>>(xyz, features, W1, b1, W2, b2,
                                                      out_xyz, gidx, out_feat);
}